// Round 4
// baseline (247.938 us; speedup 1.0000x reference)
//
#include <hip/hip_runtime.h>
#include <hip/hip_bf16.h>

using floatx4 = __attribute__((ext_vector_type(4))) float;
using int4v   = __attribute__((ext_vector_type(4))) int;
using int8v   = __attribute__((ext_vector_type(8))) int;

#define TEMP_INV 14.285714285714286f  // 1/0.07
#define DD 256   // feature dim; one fp8 row = 256 B
#define BM 128
#define NCT 4    // column tiles per block
#define SC1 127  // e8m0 exponent 127 -> scale 1.0

typedef const __attribute__((address_space(1))) unsigned int* gptr_t;
typedef __attribute__((address_space(3))) unsigned int* lptr_t;

__device__ __forceinline__ void async_cp16(const void* g, void* l) {
  __builtin_amdgcn_global_load_lds((gptr_t)g, (lptr_t)l, 16, 0, 0);
}

// ---------------- kernel 1: L2 normalize rows, cast to fp8 e4m3 -------------
__global__ __launch_bounds__(256) void nrm_kernel(
    const float* __restrict__ anchor, const float* __restrict__ positive,
    unsigned char* __restrict__ a8, unsigned char* __restrict__ p8) {
  const int wave = threadIdx.x >> 6;
  const int lane = threadIdx.x & 63;
  const int row  = blockIdx.x * 2 + (wave & 1);
  const float* src = (wave < 2) ? anchor : positive;
  unsigned char* dst = (wave < 2) ? a8 : p8;
  const float4 v = ((const float4*)(src + (size_t)row * DD))[lane];
  float ss = v.x * v.x + v.y * v.y + v.z * v.z + v.w * v.w;
#pragma unroll
  for (int m = 32; m >= 1; m >>= 1) ss += __shfl_xor(ss, m, 64);
  const float scale = 1.0f / fmaxf(sqrtf(ss), 1e-12f);
  int pk = __builtin_amdgcn_cvt_pk_fp8_f32(v.x * scale, v.y * scale, 0, false);
  pk     = __builtin_amdgcn_cvt_pk_fp8_f32(v.z * scale, v.w * scale, pk, true);
  ((int*)(dst + (size_t)row * DD))[lane] = pk;
}

// B-fragment read from swizzled LDS tile: slot (row, c) holds global granule
// c ^ (row&15); returns the 32 global bytes [ks*128+quad*32 .. +32) of `row`.
__device__ __forceinline__ int8v bfrag(const unsigned char* Bs, int row, int ks,
                                       int quad, int l16) {
  const int c0 = ks * 8 + quad * 2;
  const int4v lo = *(const int4v*)(Bs + row * DD + (((c0 + 0) ^ l16) << 4));
  const int4v hi = *(const int4v*)(Bs + row * DD + (((c0 + 1) ^ l16) << 4));
  return __builtin_shufflevector(lo, hi, 0, 1, 2, 3, 4, 5, 6, 7);
}

// ------ kernel 2: 128-row band x 4 column tiles, MX-fp8 MFMA, fused stats ---
// A-fragments: loaded ONCE per block from global into registers (full K).
// B: one 32 KB LDS tile per ct, staged via global_load_lds w/ XOR-16B swizzle;
// next tile's staging is issued before this tile's MFMAs+epilogue (pipelined).
__global__ __launch_bounds__(256, 2) void gemm_stats(
    const unsigned char* __restrict__ a8, const unsigned char* __restrict__ p8,
    float* __restrict__ rsum, float* __restrict__ rmax,
    float* __restrict__ diag, int Btot) {
  __shared__ __align__(16) unsigned char Bs[BM * DD];  // 32 KB
  __shared__ float red_sum[2][BM];
  __shared__ float red_max[2][BM];

  const int t = threadIdx.x;
  const int wave = t >> 6, lane = t & 63;
  const int wm = wave & 1, wn = wave >> 1;
  const int quad = lane >> 4, l16 = lane & 15;
  const int row0    = blockIdx.y * BM;
  const int colbase = blockIdx.x * (NCT * BM);

  // staging decomposition: lane = r4*16 + cg ; dest row&15 = wave*4+r4
  const int r4   = lane >> 4;
  const int cg   = lane & 15;
  const int csrc = cg ^ (wave * 4 + r4);

  // ---- A fragments straight from global (L2-resident), kept in VGPRs ----
  int8v af[4][2];
#pragma unroll
  for (int mi = 0; mi < 4; ++mi)
#pragma unroll
    for (int ks = 0; ks < 2; ++ks)
      af[mi][ks] = *(const int8v*)(a8 +
          (size_t)(row0 + wm * 64 + mi * 16 + l16) * DD + ks * 128 + quad * 32);

  // ---- prefetch B tile for ct=0 ----
#pragma unroll
  for (int q = 0; q < 8; ++q)
    async_cp16(p8 + (size_t)(colbase + q * 16 + wave * 4 + r4) * DD + csrc * 16,
               &Bs[(q * 16 + wave * 4) * DD]);

  float se_run[4][4], mx_run[4][4];
#pragma unroll
  for (int a = 0; a < 4; ++a)
#pragma unroll
    for (int b = 0; b < 4; ++b) { se_run[a][b] = 0.f; mx_run[a][b] = -INFINITY; }

  for (int ct = 0; ct < NCT; ++ct) {
    __syncthreads();  // B[ct] staged & visible (vmcnt drain here, covered)

    floatx4 acc[4][4];
#pragma unroll
    for (int a = 0; a < 4; ++a)
#pragma unroll
      for (int b = 0; b < 4; ++b) acc[a][b] = (floatx4){0.f, 0.f, 0.f, 0.f};

    // kstep 1 first: consume bf1, then load bf0, so only one frag set is
    // live at the barrier.
    int8v bf1[4];
#pragma unroll
    for (int ni = 0; ni < 4; ++ni) bf1[ni] = bfrag(Bs, wn * 64 + ni * 16 + l16, 1, quad, l16);
#pragma unroll
    for (int mi = 0; mi < 4; ++mi)
#pragma unroll
      for (int ni = 0; ni < 4; ++ni)
        acc[mi][ni] = __builtin_amdgcn_mfma_scale_f32_16x16x128_f8f6f4(
            af[mi][1], bf1[ni], acc[mi][ni], 0, 0, 0, SC1, 0, SC1);

    int8v bf0[4];
#pragma unroll
    for (int ni = 0; ni < 4; ++ni) bf0[ni] = bfrag(Bs, wn * 64 + ni * 16 + l16, 0, quad, l16);

    __syncthreads();  // all waves' reads of Bs are in registers now
    if (ct + 1 < NCT) {  // issue next tile's staging; overlaps MFMA+epilogue
      const int colb = colbase + (ct + 1) * BM;
#pragma unroll
      for (int q = 0; q < 8; ++q)
        async_cp16(p8 + (size_t)(colb + q * 16 + wave * 4 + r4) * DD + csrc * 16,
                   &Bs[(q * 16 + wave * 4) * DD]);
    }

#pragma unroll
    for (int mi = 0; mi < 4; ++mi)
#pragma unroll
      for (int ni = 0; ni < 4; ++ni)
        acc[mi][ni] = __builtin_amdgcn_mfma_scale_f32_16x16x128_f8f6f4(
            af[mi][0], bf0[ni], acc[mi][ni], 0, 0, 0, SC1, 0, SC1);

    // ---- fused stats epilogue (C/D layout: col=lane&15, row=quad*4+reg) ----
    const int col0 = colbase + ct * BM;
#pragma unroll
    for (int mi = 0; mi < 4; ++mi) {
#pragma unroll
      for (int reg = 0; reg < 4; ++reg) {
        const int i = row0 + wm * 64 + mi * 16 + quad * 4 + reg;
#pragma unroll
        for (int ni = 0; ni < 4; ++ni) {
          const float s = acc[mi][ni][reg];
          const int j = col0 + wn * 64 + ni * 16 + l16;
          se_run[mi][reg] += __expf(s * TEMP_INV);
          if (i == j) diag[i] = s;  // every diagonal elem hit exactly once
          else mx_run[mi][reg] = fmaxf(mx_run[mi][reg], s);
        }
      }
    }
  }

  // once-per-block 16-lane cross reduction
#pragma unroll
  for (int mi = 0; mi < 4; ++mi) {
#pragma unroll
    for (int reg = 0; reg < 4; ++reg) {
      float se = se_run[mi][reg], mx = mx_run[mi][reg];
#pragma unroll
      for (int m = 1; m < 16; m <<= 1) {
        se += __shfl_xor(se, m, 64);
        mx = fmaxf(mx, __shfl_xor(mx, m, 64));
      }
      if (l16 == 0) {
        const int rb = wm * 64 + mi * 16 + quad * 4 + reg;
        red_sum[wn][rb] = se;
        red_max[wn][rb] = mx;
      }
    }
  }
  __syncthreads();
  if (t < BM) {
    rsum[(size_t)blockIdx.x * Btot + row0 + t] = red_sum[0][t] + red_sum[1][t];
    rmax[(size_t)blockIdx.x * Btot + row0 + t] = fmaxf(red_max[0][t], red_max[1][t]);
  }
}

// ---------------- kernel 3: reduce column-group partials per row ----------
__global__ __launch_bounds__(256) void row_loss_kernel(
    const float* __restrict__ rsum, const float* __restrict__ rmax,
    const float* __restrict__ diag, float* __restrict__ rloss, int Btot, int NG) {
  const int i = blockIdx.x * 256 + threadIdx.x;
  float s = 0.f, m = -INFINITY;
  for (int c = 0; c < NG; ++c) {
    s += rsum[(size_t)c * Btot + i];
    m = fmaxf(m, rmax[(size_t)c * Btot + i]);
  }
  rloss[i] = __logf(s + __expf(m * TEMP_INV)) - diag[i] * TEMP_INV;
}

// ---------------- kernel 4: mean over rows -> scalar --------------------
__global__ __launch_bounds__(256) void final_reduce(
    const float* __restrict__ rloss, float* __restrict__ out, int Btot) {
  float s = 0.f;
  for (int k = threadIdx.x; k < Btot; k += 256) s += rloss[k];
#pragma unroll
  for (int m = 32; m >= 1; m >>= 1) s += __shfl_xor(s, m, 64);
  __shared__ float red[4];
  if ((threadIdx.x & 63) == 0) red[threadIdx.x >> 6] = s;
  __syncthreads();
  if (threadIdx.x == 0) out[0] = (red[0] + red[1] + red[2] + red[3]) / (float)Btot;
}

extern "C" void kernel_launch(void* const* d_in, const int* in_sizes, int n_in,
                              void* d_out, int out_size, void* d_ws, size_t ws_size,
                              hipStream_t stream) {
  const float* anchor   = (const float*)d_in[0];
  const float* positive = (const float*)d_in[1];
  const int B  = in_sizes[0] / DD;     // 8192
  const int NG = B / (BM * NCT);       // 16 column groups
  const size_t BD = (size_t)B * DD;

  // ws: a8(2MB) | p8(2MB) | rsum(NG*B) | rmax(NG*B) | diag(B) | rloss(B)
  unsigned char* a8 = (unsigned char*)d_ws;
  unsigned char* p8 = a8 + BD;
  float* rsum  = (float*)(p8 + BD);
  float* rmax  = rsum + (size_t)NG * B;
  float* diag  = rmax + (size_t)NG * B;
  float* rloss = diag + B;

  nrm_kernel<<<B / 2, 256, 0, stream>>>(anchor, positive, a8, p8);
  dim3 g2(NG, B / BM);
  gemm_stats<<<g2, 256, 0, stream>>>(a8, p8, rsum, rmax, diag, B);
  row_loss_kernel<<<B / 256, 256, 0, stream>>>(rsum, rmax, diag, rloss, B, NG);
  final_reduce<<<1, 256, 0, stream>>>(rloss, (float*)d_out, B);
}

// Round 5
// 133.939 us; speedup vs baseline: 1.8511x; 1.8511x over previous
//
#include <hip/hip_runtime.h>
#include <hip/hip_bf16.h>

using floatx4 = __attribute__((ext_vector_type(4))) float;
using int4v   = __attribute__((ext_vector_type(4))) int;
using int8v   = __attribute__((ext_vector_type(8))) int;

#define TEMP_INV 14.285714285714286f  // 1/0.07
#define DD 256   // feature dim; one fp8 row = 256 B
#define BM 128
#define NCT 4    // column tiles per block
#define SC1 127  // e8m0 exponent 127 -> scale 1.0

typedef const __attribute__((address_space(1))) unsigned int* gptr_t;
typedef __attribute__((address_space(3))) unsigned int* lptr_t;

__device__ __forceinline__ void async_cp16(const void* g, void* l) {
  __builtin_amdgcn_global_load_lds((gptr_t)g, (lptr_t)l, 16, 0, 0);
}

// ---------------- kernel 1: L2 normalize rows, cast to fp8 e4m3 -------------
__global__ __launch_bounds__(256) void nrm_kernel(
    const float* __restrict__ anchor, const float* __restrict__ positive,
    unsigned char* __restrict__ a8, unsigned char* __restrict__ p8) {
  const int wave = threadIdx.x >> 6;
  const int lane = threadIdx.x & 63;
  const int row  = blockIdx.x * 2 + (wave & 1);
  const float* src = (wave < 2) ? anchor : positive;
  unsigned char* dst = (wave < 2) ? a8 : p8;
  const float4 v = ((const float4*)(src + (size_t)row * DD))[lane];
  float ss = v.x * v.x + v.y * v.y + v.z * v.z + v.w * v.w;
#pragma unroll
  for (int m = 32; m >= 1; m >>= 1) ss += __shfl_xor(ss, m, 64);
  const float scale = 1.0f / fmaxf(sqrtf(ss), 1e-12f);
  int pk = __builtin_amdgcn_cvt_pk_fp8_f32(v.x * scale, v.y * scale, 0, false);
  pk     = __builtin_amdgcn_cvt_pk_fp8_f32(v.z * scale, v.w * scale, pk, true);
  ((int*)(dst + (size_t)row * DD))[lane] = pk;
}

// B-fragment read from swizzled LDS tile: slot (row, c) holds global granule
// c ^ (row&15); returns the 32 global bytes [ks*128+quad*32 .. +32) of `row`.
__device__ __forceinline__ int8v bfrag(const unsigned char* Bs, int row, int ks,
                                       int quad, int l16) {
  const int c0 = ks * 8 + quad * 2;
  const int4v lo = *(const int4v*)(Bs + row * DD + (((c0 + 0) ^ l16) << 4));
  const int4v hi = *(const int4v*)(Bs + row * DD + (((c0 + 1) ^ l16) << 4));
  return __builtin_shufflevector(lo, hi, 0, 1, 2, 3, 4, 5, 6, 7);
}

// ------ kernel 2: 128-row band x 4 column tiles, MX-fp8 MFMA, fused stats ---
// A-fragments: loaded ONCE per block from global into registers (64 VGPRs,
// deliberate). B-fragments: read transiently one ni at a time (8 VGPRs live)
// -- R3's bf0[]/bf1[] pre-read blew the register budget and spilled.
__global__ __launch_bounds__(256) void gemm_stats(
    const unsigned char* __restrict__ a8, const unsigned char* __restrict__ p8,
    float* __restrict__ rsum, float* __restrict__ rmax,
    float* __restrict__ diag, int Btot) {
  __shared__ __align__(16) unsigned char Bs[BM * DD];  // 32 KB
  __shared__ float red_sum[2][BM];
  __shared__ float red_max[2][BM];

  const int t = threadIdx.x;
  const int wave = t >> 6, lane = t & 63;
  const int wm = wave & 1, wn = wave >> 1;
  const int quad = lane >> 4, l16 = lane & 15;
  const int row0    = blockIdx.y * BM;
  const int colbase = blockIdx.x * (NCT * BM);

  // staging decomposition: lane = r4*16 + cg ; dest row&15 = wave*4+r4
  const int r4   = lane >> 4;
  const int cg   = lane & 15;
  const int csrc = cg ^ (wave * 4 + r4);

  // ---- A fragments straight from global (L2-resident), kept in VGPRs ----
  int8v af[4][2];
#pragma unroll
  for (int mi = 0; mi < 4; ++mi)
#pragma unroll
    for (int ks = 0; ks < 2; ++ks)
      af[mi][ks] = *(const int8v*)(a8 +
          (size_t)(row0 + wm * 64 + mi * 16 + l16) * DD + ks * 128 + quad * 32);

  // ---- prefetch B tile for ct=0 ----
#pragma unroll
  for (int q = 0; q < 8; ++q)
    async_cp16(p8 + (size_t)(colbase + q * 16 + wave * 4 + r4) * DD + csrc * 16,
               &Bs[(q * 16 + wave * 4) * DD]);

  float se_run[4][4], mx_run[4][4];
#pragma unroll
  for (int a = 0; a < 4; ++a)
#pragma unroll
    for (int b = 0; b < 4; ++b) { se_run[a][b] = 0.f; mx_run[a][b] = -INFINITY; }

  for (int ct = 0; ct < NCT; ++ct) {
    __syncthreads();  // Bs[ct] staged & visible

    floatx4 acc[4][4];
#pragma unroll
    for (int a = 0; a < 4; ++a)
#pragma unroll
      for (int b = 0; b < 4; ++b) acc[a][b] = (floatx4){0.f, 0.f, 0.f, 0.f};

#pragma unroll
    for (int ks = 0; ks < 2; ++ks) {
#pragma unroll
      for (int ni = 0; ni < 4; ++ni) {
        const int8v bf = bfrag(Bs, wn * 64 + ni * 16 + l16, ks, quad, l16);
#pragma unroll
        for (int mi = 0; mi < 4; ++mi)
          acc[mi][ni] = __builtin_amdgcn_mfma_scale_f32_16x16x128_f8f6f4(
              af[mi][ks], bf, acc[mi][ni], 0, 0, 0, SC1, 0, SC1);
      }
    }

    __syncthreads();  // all waves done reading Bs
    if (ct + 1 < NCT) {  // issue next tile's staging; overlaps epilogue below
      const int colb = colbase + (ct + 1) * BM;
#pragma unroll
      for (int q = 0; q < 8; ++q)
        async_cp16(p8 + (size_t)(colb + q * 16 + wave * 4 + r4) * DD + csrc * 16,
                   &Bs[(q * 16 + wave * 4) * DD]);
    }

    // ---- fused stats epilogue (C/D layout: col=lane&15, row=quad*4+reg) ----
    const int col0 = colbase + ct * BM;
#pragma unroll
    for (int mi = 0; mi < 4; ++mi) {
#pragma unroll
      for (int reg = 0; reg < 4; ++reg) {
        const int i = row0 + wm * 64 + mi * 16 + quad * 4 + reg;
#pragma unroll
        for (int ni = 0; ni < 4; ++ni) {
          const float s = acc[mi][ni][reg];
          const int j = col0 + wn * 64 + ni * 16 + l16;
          se_run[mi][reg] += __expf(s * TEMP_INV);
          if (i == j) diag[i] = s;  // every diagonal elem hit exactly once
          else mx_run[mi][reg] = fmaxf(mx_run[mi][reg], s);
        }
      }
    }
  }

  // once-per-block 16-lane cross reduction
#pragma unroll
  for (int mi = 0; mi < 4; ++mi) {
#pragma unroll
    for (int reg = 0; reg < 4; ++reg) {
      float se = se_run[mi][reg], mx = mx_run[mi][reg];
#pragma unroll
      for (int m = 1; m < 16; m <<= 1) {
        se += __shfl_xor(se, m, 64);
        mx = fmaxf(mx, __shfl_xor(mx, m, 64));
      }
      if (l16 == 0) {
        const int rb = wm * 64 + mi * 16 + quad * 4 + reg;
        red_sum[wn][rb] = se;
        red_max[wn][rb] = mx;
      }
    }
  }
  __syncthreads();
  if (t < BM) {
    rsum[(size_t)blockIdx.x * Btot + row0 + t] = red_sum[0][t] + red_sum[1][t];
    rmax[(size_t)blockIdx.x * Btot + row0 + t] = fmaxf(red_max[0][t], red_max[1][t]);
  }
}

// ---------------- kernel 3: reduce column-group partials per row ----------
__global__ __launch_bounds__(256) void row_loss_kernel(
    const float* __restrict__ rsum, const float* __restrict__ rmax,
    const float* __restrict__ diag, float* __restrict__ rloss, int Btot, int NG) {
  const int i = blockIdx.x * 256 + threadIdx.x;
  float s = 0.f, m = -INFINITY;
  for (int c = 0; c < NG; ++c) {
    s += rsum[(size_t)c * Btot + i];
    m = fmaxf(m, rmax[(size_t)c * Btot + i]);
  }
  rloss[i] = __logf(s + __expf(m * TEMP_INV)) - diag[i] * TEMP_INV;
}

// ---------------- kernel 4: mean over rows -> scalar --------------------
__global__ __launch_bounds__(256) void final_reduce(
    const float* __restrict__ rloss, float* __restrict__ out, int Btot) {
  float s = 0.f;
  for (int k = threadIdx.x; k < Btot; k += 256) s += rloss[k];
#pragma unroll
  for (int m = 32; m >= 1; m >>= 1) s += __shfl_xor(s, m, 64);
  __shared__ float red[4];
  if ((threadIdx.x & 63) == 0) red[threadIdx.x >> 6] = s;
  __syncthreads();
  if (threadIdx.x == 0) out[0] = (red[0] + red[1] + red[2] + red[3]) / (float)Btot;
}

extern "C" void kernel_launch(void* const* d_in, const int* in_sizes, int n_in,
                              void* d_out, int out_size, void* d_ws, size_t ws_size,
                              hipStream_t stream) {
  const float* anchor   = (const float*)d_in[0];
  const float* positive = (const float*)d_in[1];
  const int B  = in_sizes[0] / DD;     // 8192
  const int NG = B / (BM * NCT);       // 16 column groups
  const size_t BD = (size_t)B * DD;

  // ws: a8(2MB) | p8(2MB) | rsum(NG*B) | rmax(NG*B) | diag(B) | rloss(B)
  unsigned char* a8 = (unsigned char*)d_ws;
  unsigned char* p8 = a8 + BD;
  float* rsum  = (float*)(p8 + BD);
  float* rmax  = rsum + (size_t)NG * B;
  float* diag  = rmax + (size_t)NG * B;
  float* rloss = diag + B;

  nrm_kernel<<<B / 2, 256, 0, stream>>>(anchor, positive, a8, p8);
  dim3 g2(NG, B / BM);
  gemm_stats<<<g2, 256, 0, stream>>>(a8, p8, rsum, rmax, diag, B);
  row_loss_kernel<<<B / 256, 256, 0, stream>>>(rsum, rmax, diag, rloss, B, NG);
  final_reduce<<<1, 256, 0, stream>>>(rloss, (float*)d_out, B);
}

// Round 7
// 118.574 us; speedup vs baseline: 2.0910x; 1.1296x over previous
//
#include <hip/hip_runtime.h>
#include <hip/hip_bf16.h>

using floatx4 = __attribute__((ext_vector_type(4))) float;
using int4v   = __attribute__((ext_vector_type(4))) int;
using int8v   = __attribute__((ext_vector_type(8))) int;

#define TEMP_INV 14.285714285714286f  // 1/0.07
#define DD 256   // feature dim; one fp8 row = 256 B
#define BM 128
#define NCT 4    // column tiles per block
#define SC1 127  // e8m0 exponent 127 -> scale 1.0

typedef const __attribute__((address_space(1))) unsigned int* gptr_t;
typedef __attribute__((address_space(3))) unsigned int* lptr_t;

__device__ __forceinline__ void async_cp16(const void* g, void* l) {
  __builtin_amdgcn_global_load_lds((gptr_t)g, (lptr_t)l, 16, 0, 0);
}

// ---- kernel 1: L2 normalize rows -> fp8 e4m3, plus exact fp8 diag dot ----
// Each wave handles one row r for BOTH anchor and positive; diag[r] is the
// fp32 dot of the QUANTIZED rows (bit-identical inputs to what MFMA sees).
__global__ __launch_bounds__(256) void nrm_kernel(
    const float* __restrict__ anchor, const float* __restrict__ positive,
    unsigned char* __restrict__ a8, unsigned char* __restrict__ p8,
    float* __restrict__ diag) {
  const int wave = threadIdx.x >> 6;
  const int lane = threadIdx.x & 63;
  const int row  = blockIdx.x * 4 + wave;
  const float4 va = ((const float4*)(anchor   + (size_t)row * DD))[lane];
  const float4 vp = ((const float4*)(positive + (size_t)row * DD))[lane];
  float sa = va.x * va.x + va.y * va.y + va.z * va.z + va.w * va.w;
  float sp = vp.x * vp.x + vp.y * vp.y + vp.z * vp.z + vp.w * vp.w;
#pragma unroll
  for (int m = 32; m >= 1; m >>= 1) {
    sa += __shfl_xor(sa, m, 64);
    sp += __shfl_xor(sp, m, 64);
  }
  const float ka = 1.0f / fmaxf(sqrtf(sa), 1e-12f);
  const float kp = 1.0f / fmaxf(sqrtf(sp), 1e-12f);
  int pa = __builtin_amdgcn_cvt_pk_fp8_f32(va.x * ka, va.y * ka, 0, false);
  pa     = __builtin_amdgcn_cvt_pk_fp8_f32(va.z * ka, va.w * ka, pa, true);
  int pp = __builtin_amdgcn_cvt_pk_fp8_f32(vp.x * kp, vp.y * kp, 0, false);
  pp     = __builtin_amdgcn_cvt_pk_fp8_f32(vp.z * kp, vp.w * kp, pp, true);
  ((int*)(a8 + (size_t)row * DD))[lane] = pa;
  ((int*)(p8 + (size_t)row * DD))[lane] = pp;
  // exact quantized dot for the diagonal (byte selector must be literal)
  float d = __builtin_amdgcn_cvt_f32_fp8(pa, 0) * __builtin_amdgcn_cvt_f32_fp8(pp, 0)
          + __builtin_amdgcn_cvt_f32_fp8(pa, 1) * __builtin_amdgcn_cvt_f32_fp8(pp, 1)
          + __builtin_amdgcn_cvt_f32_fp8(pa, 2) * __builtin_amdgcn_cvt_f32_fp8(pp, 2)
          + __builtin_amdgcn_cvt_f32_fp8(pa, 3) * __builtin_amdgcn_cvt_f32_fp8(pp, 3);
#pragma unroll
  for (int m = 32; m >= 1; m >>= 1) d += __shfl_xor(d, m, 64);
  if (lane == 0) diag[row] = d;
}

// B-fragment read from swizzled LDS tile: slot (row, c) holds global granule
// c ^ (row&15); returns the 32 global bytes [ks*128+quad*32 .. +32) of `row`.
__device__ __forceinline__ int8v bfrag(const unsigned char* Bs, int row, int ks,
                                       int quad, int l16) {
  const int c0 = ks * 8 + quad * 2;
  const int4v lo = *(const int4v*)(Bs + row * DD + (((c0 + 0) ^ l16) << 4));
  const int4v hi = *(const int4v*)(Bs + row * DD + (((c0 + 1) ^ l16) << 4));
  return __builtin_shufflevector(lo, hi, 0, 1, 2, 3, 4, 5, 6, 7);
}

// ------ kernel 2: 512 threads / 8 waves, 32x64 frags per wave ------
// acc 32 + af 32 + stats 16 VGPRs -> <=128/wave (4 waves/SIMD, 16 waves/CU).
// No global stores in the main loop (diag handled in nrm_kernel).
__global__ __launch_bounds__(512, 4) void gemm_stats(
    const unsigned char* __restrict__ a8, const unsigned char* __restrict__ p8,
    float* __restrict__ rsum, float* __restrict__ rmax, int Btot) {
  __shared__ __align__(16) unsigned char Bs[BM * DD];  // 32 KB
  __shared__ float red_sum[2][BM];
  __shared__ float red_max[2][BM];

  const int t = threadIdx.x;
  const int wave = t >> 6, lane = t & 63;
  const int wm = wave & 3, wn = wave >> 2;      // 4 row-groups x 2 col-groups
  const int quad = lane >> 4, l16 = lane & 15;
  const int row0    = blockIdx.y * BM;
  const int colbase = blockIdx.x * (NCT * BM);
  const bool hasdiag = ((int)(blockIdx.y >> 2) == (int)blockIdx.x);

  // staging decomposition: lane = r4*16 + cg
  const int r4   = lane >> 4;
  const int cg   = lane & 15;

  // ---- A fragments: 2 mi x 2 ks, loaded once (32 VGPRs) ----
  int8v af[2][2];
#pragma unroll
  for (int mi = 0; mi < 2; ++mi)
#pragma unroll
    for (int ks = 0; ks < 2; ++ks)
      af[mi][ks] = *(const int8v*)(a8 +
          (size_t)(row0 + wm * 32 + mi * 16 + l16) * DD + ks * 128 + quad * 32);

  // ---- prefetch B tile for ct=0: each wave 4 issues of 4 rows ----
#pragma unroll
  for (int q = 0; q < 4; ++q) {
    const int rb = q * 32 + wave * 4;           // wave-uniform base row
    const int r  = rb + r4;
    async_cp16(p8 + (size_t)(colbase + r) * DD + (cg ^ (r & 15)) * 16,
               &Bs[rb * DD]);
  }

  float se_run[2][4], mx_run[2][4];
#pragma unroll
  for (int a = 0; a < 2; ++a)
#pragma unroll
    for (int b = 0; b < 4; ++b) { se_run[a][b] = 0.f; mx_run[a][b] = -INFINITY; }

  for (int ct = 0; ct < NCT; ++ct) {
    __syncthreads();  // Bs[ct] staged & visible

    floatx4 acc[2][4];
#pragma unroll
    for (int a = 0; a < 2; ++a)
#pragma unroll
      for (int b = 0; b < 4; ++b) acc[a][b] = (floatx4){0.f, 0.f, 0.f, 0.f};

#pragma unroll
    for (int ks = 0; ks < 2; ++ks) {
#pragma unroll
      for (int ni = 0; ni < 4; ++ni) {
        const int8v bf = bfrag(Bs, wn * 64 + ni * 16 + l16, ks, quad, l16);
#pragma unroll
        for (int mi = 0; mi < 2; ++mi)
          acc[mi][ni] = __builtin_amdgcn_mfma_scale_f32_16x16x128_f8f6f4(
              af[mi][ks], bf, acc[mi][ni], 0, 0, 0, SC1, 0, SC1);
      }
    }

    __syncthreads();  // all waves done reading Bs
    if (ct + 1 < NCT) {  // issue next tile's staging; overlaps epilogue below
      const int colb = colbase + (ct + 1) * BM;
#pragma unroll
      for (int q = 0; q < 4; ++q) {
        const int rb = q * 32 + wave * 4;
        const int r  = rb + r4;
        async_cp16(p8 + (size_t)(colb + r) * DD + (cg ^ (r & 15)) * 16,
                   &Bs[rb * DD]);
      }
    }

    // ---- fused stats epilogue (C/D: col=lane&15, row=quad*4+reg) ----
    const int col0 = colbase + ct * BM;
    if (!hasdiag) {
#pragma unroll
      for (int mi = 0; mi < 2; ++mi)
#pragma unroll
        for (int reg = 0; reg < 4; ++reg)
#pragma unroll
          for (int ni = 0; ni < 4; ++ni) {
            const float s = acc[mi][ni][reg];
            se_run[mi][reg] += __expf(s * TEMP_INV);
            mx_run[mi][reg] = fmaxf(mx_run[mi][reg], s);
          }
    } else {
#pragma unroll
      for (int mi = 0; mi < 2; ++mi)
#pragma unroll
        for (int reg = 0; reg < 4; ++reg) {
          const int i = row0 + wm * 32 + mi * 16 + quad * 4 + reg;
#pragma unroll
          for (int ni = 0; ni < 4; ++ni) {
            const float s = acc[mi][ni][reg];
            const int j = col0 + wn * 64 + ni * 16 + l16;
            se_run[mi][reg] += __expf(s * TEMP_INV);
            mx_run[mi][reg] = fmaxf(mx_run[mi][reg], (i == j) ? -INFINITY : s);
          }
        }
    }
  }

  // once-per-block 16-lane cross reduction
#pragma unroll
  for (int mi = 0; mi < 2; ++mi) {
#pragma unroll
    for (int reg = 0; reg < 4; ++reg) {
      float se = se_run[mi][reg], mx = mx_run[mi][reg];
#pragma unroll
      for (int m = 1; m < 16; m <<= 1) {
        se += __shfl_xor(se, m, 64);
        mx = fmaxf(mx, __shfl_xor(mx, m, 64));
      }
      if (l16 == 0) {
        const int rb = wm * 32 + mi * 16 + quad * 4 + reg;
        red_sum[wn][rb] = se;
        red_max[wn][rb] = mx;
      }
    }
  }
  __syncthreads();
  if (t < BM) {
    rsum[(size_t)blockIdx.x * Btot + row0 + t] = red_sum[0][t] + red_sum[1][t];
    rmax[(size_t)blockIdx.x * Btot + row0 + t] = fmaxf(red_max[0][t], red_max[1][t]);
  }
}

// ---- kernel 3: per-row loss from partials, block-reduce, atomic mean ----
__global__ __launch_bounds__(256) void row_loss_kernel(
    const float* __restrict__ rsum, const float* __restrict__ rmax,
    const float* __restrict__ diag, float* __restrict__ out, int Btot, int NG) {
  const int i = blockIdx.x * 256 + threadIdx.x;
  float s = 0.f, m = -INFINITY;
  for (int c = 0; c < NG; ++c) {
    s += rsum[(size_t)c * Btot + i];
    m = fmaxf(m, rmax[(size_t)c * Btot + i]);
  }
  float rl = __logf(s + __expf(m * TEMP_INV)) - diag[i] * TEMP_INV;
#pragma unroll
  for (int mm = 32; mm >= 1; mm >>= 1) rl += __shfl_xor(rl, mm, 64);
  __shared__ float red[4];
  if ((threadIdx.x & 63) == 0) red[threadIdx.x >> 6] = rl;
  __syncthreads();
  if (threadIdx.x == 0)
    atomicAdd(out, (red[0] + red[1] + red[2] + red[3]) / (float)Btot);
}

extern "C" void kernel_launch(void* const* d_in, const int* in_sizes, int n_in,
                              void* d_out, int out_size, void* d_ws, size_t ws_size,
                              hipStream_t stream) {
  const float* anchor   = (const float*)d_in[0];
  const float* positive = (const float*)d_in[1];
  const int B  = in_sizes[0] / DD;     // 8192
  const int NG = B / (BM * NCT);       // 16 column groups
  const size_t BD = (size_t)B * DD;

  // ws: a8(2MB) | p8(2MB) | rsum(NG*B) | rmax(NG*B) | diag(B)
  unsigned char* a8 = (unsigned char*)d_ws;
  unsigned char* p8 = a8 + BD;
  float* rsum  = (float*)(p8 + BD);
  float* rmax  = rsum + (size_t)NG * B;
  float* diag  = rmax + (size_t)NG * B;

  (void)hipMemsetAsync(d_out, 0, sizeof(float), stream);
  nrm_kernel<<<B / 4, 256, 0, stream>>>(anchor, positive, a8, p8, diag);
  dim3 g2(NG, B / BM);
  gemm_stats<<<g2, 512, 0, stream>>>(a8, p8, rsum, rmax, B);
  row_loss_kernel<<<B / 256, 256, 0, stream>>>(rsum, rmax, diag, (float*)d_out, B, NG);
}